// Round 5
// baseline (719.326 us; speedup 1.0000x reference)
//
#include <hip/hip_runtime.h>

typedef unsigned short u16;
typedef unsigned int u32;
typedef __bf16 bf16x8 __attribute__((ext_vector_type(8)));
typedef float f32x4 __attribute__((ext_vector_type(4)));

__device__ __forceinline__ float bf2f(u16 b) {
    return __uint_as_float(((u32)b) << 16);
}
__device__ __forceinline__ u16 f2bf(float f) {
    u32 u = __float_as_uint(f);
    return (u16)((u + 0x7fffu + ((u >> 16) & 1u)) >> 16);
}

// fp32 canonical param block (element offsets)
#define P_CONVW 0       // 2048*4
#define P_CONVB 8192    // 2048
#define P_ALOG  10240   // 2048*16
#define P_DPAR  43008   // 2048
#define P_DTW   45056   // 2048
#define P_DTB   47104   // 2048
#define P_LNG   49152   // 2048
#define P_LNB   51200   // 2048
#define P_TOTAL 53248

struct ParamPtrs { const void* p[8]; };

// dtype detected from D_param (== ones): bf16 -> first u16 = 0x3F80; fp32 ->
// first (low) u16 of 1.0f = 0x0000.  (Evidence says fp32; detection is free
// insurance.)
__global__ __launch_bounds__(256) void canon_params(ParamPtrs pp, float* __restrict__ dst,
                                                    const u16* __restrict__ dp) {
    const bool isbf = (dp[0] != 0);
    const int i = blockIdx.x * 256 + threadIdx.x;  // exact grid over P_TOTAL
    int seg, off;
    if (i < P_CONVB)      { seg = 0; off = i; }
    else if (i < P_ALOG)  { seg = 1; off = i - P_CONVB; }
    else if (i < P_DPAR)  { seg = 2; off = i - P_ALOG; }
    else if (i < P_DTW)   { seg = 3; off = i - P_DPAR; }
    else if (i < P_DTB)   { seg = 4; off = i - P_DTW; }
    else if (i < P_LNG)   { seg = 5; off = i - P_DTB; }
    else if (i < P_LNB)   { seg = 6; off = i - P_LNG; }
    else                  { seg = 7; off = i - P_LNB; }
    dst[i] = isbf ? bf2f(((const u16*)pp.p[seg])[off]) : ((const float*)pp.p[seg])[off];
}

// load 8 consecutive elements as packed bf16 (uint4) from a bf16 OR fp32 source
__device__ __forceinline__ uint4 load8(const void* __restrict__ base, size_t off, bool isbf) {
    if (isbf) {
        return *(const uint4*)((const u16*)base + off);
    } else {
        const float4* p = (const float4*)((const float*)base + off);
        const float4 v0 = p[0], v1 = p[1];
        uint4 o;
        o.x = (u32)f2bf(v0.x) | ((u32)f2bf(v0.y) << 16);
        o.y = (u32)f2bf(v0.z) | ((u32)f2bf(v0.w) << 16);
        o.z = (u32)f2bf(v1.x) | ((u32)f2bf(v1.y) << 16);
        o.w = (u32)f2bf(v1.z) | ((u32)f2bf(v1.w) << 16);
        return o;
    }
}

// ---------------------------------------------------------------------------
// GEMM: C[M,N] = A[M,K] * W[N,K]^T.  STORE_F32: fp32 C, else bf16 C.
// 128x128 tile, 4 waves (2x2), 4x4 frags of 16x16, MFMA 16x16x32 bf16.
// ---------------------------------------------------------------------------
template <bool A_BF16_FIXED, bool STORE_F32>
__global__ __launch_bounds__(256) void gemm_bt(const void* __restrict__ A,
                                               const void* __restrict__ Bw,
                                               void* __restrict__ C,
                                               int M, int N, int K,
                                               const u16* __restrict__ dp) {
    const bool wbf = (dp[0] != 0);
    const bool abf = A_BF16_FIXED ? true : wbf;
    const int bm = blockIdx.x;
    const int bn = blockIdx.y;
    const int tid = threadIdx.x;
    const int lane = tid & 63;
    const int wave = tid >> 6;
    const int wm = wave >> 1, wn = wave & 1;
    const int l16 = lane & 15, quad = lane >> 4;

    __shared__ __align__(16) u16 sA[128 * 40];
    __shared__ __align__(16) u16 sB[128 * 40];

    f32x4 acc[4][4] = {};

    const int r0 = tid >> 2, c0 = tid & 3;
    const int r1 = r0 + 64;

    for (int k0 = 0; k0 < K; k0 += 32) {
        const uint4 a0 = load8(A, (size_t)(bm * 128 + r0) * K + k0 + c0 * 8, abf);
        const uint4 a1 = load8(A, (size_t)(bm * 128 + r1) * K + k0 + c0 * 8, abf);
        const uint4 b0 = load8(Bw, (size_t)(bn * 128 + r0) * K + k0 + c0 * 8, wbf);
        const uint4 b1 = load8(Bw, (size_t)(bn * 128 + r1) * K + k0 + c0 * 8, wbf);
        __syncthreads();  // protect LDS from previous iteration's readers
        *(uint4*)&sA[r0 * 40 + c0 * 8] = a0;
        *(uint4*)&sA[r1 * 40 + c0 * 8] = a1;
        *(uint4*)&sB[r0 * 40 + c0 * 8] = b0;
        *(uint4*)&sB[r1 * 40 + c0 * 8] = b1;
        __syncthreads();

        bf16x8 af[4], bg[4];
#pragma unroll
        for (int t = 0; t < 4; ++t) {
            af[t] = *(const bf16x8*)&sA[(wm * 64 + t * 16 + l16) * 40 + quad * 8];
            bg[t] = *(const bf16x8*)&sB[(wn * 64 + t * 16 + l16) * 40 + quad * 8];
        }
#pragma unroll
        for (int mt = 0; mt < 4; ++mt)
#pragma unroll
            for (int nt = 0; nt < 4; ++nt)
                acc[mt][nt] = __builtin_amdgcn_mfma_f32_16x16x32_bf16(
                    af[mt], bg[nt], acc[mt][nt], 0, 0, 0);
    }

#pragma unroll
    for (int mt = 0; mt < 4; ++mt) {
#pragma unroll
        for (int r = 0; r < 4; ++r) {
            const int row = bm * 128 + wm * 64 + mt * 16 + quad * 4 + r;
#pragma unroll
            for (int nt = 0; nt < 4; ++nt) {
                const int col = bn * 128 + wn * 64 + nt * 16 + l16;
                if (STORE_F32)
                    ((float*)C)[(size_t)row * N + col] = acc[mt][nt][r];
                else
                    ((u16*)C)[(size_t)row * N + col] = f2bf(acc[mt][nt][r]);
            }
        }
    }
}

// ---------------------------------------------------------------------------
// Depthwise causal conv (D_CONV=4) + SiLU.  xz bf16 (B*L, 4096); writes xb
// fp32 (B*L, 2048).
// ---------------------------------------------------------------------------
__global__ __launch_bounds__(256) void conv_silu(const u16* __restrict__ xz,
                                                 const float* __restrict__ par,
                                                 float* __restrict__ xb) {
    const int idx = blockIdx.x * 256 + threadIdx.x;  // over 2*1024*2048
    const int d = idx & 2047;
    const int bl = idx >> 11;
    const int l = bl & 1023;
    float acc = par[P_CONVB + d];
#pragma unroll
    for (int k = 0; k < 4; ++k) {
        const int ls = l + k - 3;
        if (ls >= 0)
            acc = fmaf(bf2f(xz[(size_t)(bl + (ls - l)) * 4096 + d]),
                       par[P_CONVW + d * 4 + k], acc);
    }
    xb[idx] = acc / (1.f + __expf(-acc));
}

// ---------------------------------------------------------------------------
// x_proj: proj[row, e] = sum_d xb[row, d] * w[e, d],  e in [0,33), K=2048.
// ---------------------------------------------------------------------------
__global__ __launch_bounds__(256) void xproj(const float* __restrict__ xb,
                                             const void* __restrict__ w,
                                             float* __restrict__ proj,
                                             const u16* __restrict__ dp) {
    const bool isbf = (dp[0] != 0);
    const u16* w16 = (const u16*)w;
    const float* w32 = (const float*)w;
    const int row = blockIdx.x;
    const int tid = threadIdx.x;
    const int lane = tid & 63, wave = tid >> 6;
    float acc[33];
#pragma unroll
    for (int e = 0; e < 33; ++e) acc[e] = 0.f;
#pragma unroll
    for (int i = 0; i < 8; ++i) {
        const int d = tid + i * 256;
        const float xv = xb[(size_t)row * 2048 + d];
#pragma unroll
        for (int e = 0; e < 33; ++e) {
            const float wv = isbf ? bf2f(w16[e * 2048 + d]) : w32[e * 2048 + d];
            acc[e] = fmaf(xv, wv, acc[e]);
        }
    }
    __shared__ float red[4][33];
#pragma unroll
    for (int e = 0; e < 33; ++e) {
        float v = acc[e];
        v += __shfl_xor(v, 1);
        v += __shfl_xor(v, 2);
        v += __shfl_xor(v, 4);
        v += __shfl_xor(v, 8);
        v += __shfl_xor(v, 16);
        v += __shfl_xor(v, 32);
        acc[e] = v;
    }
    if (lane == 0) {
#pragma unroll
        for (int e = 0; e < 33; ++e) red[wave][e] = acc[e];
    }
    __syncthreads();
    if (tid < 33) {
        proj[(size_t)row * 33 + tid] =
            red[0][tid] + red[1][tid] + red[2][tid] + red[3][tid];
    }
}

// ---------------------------------------------------------------------------
// Selective scan.  Thread = (d_local, n); wave = 4 d x 16 n; block = 16 d.
// Writes y as bf16.
// ---------------------------------------------------------------------------
#define SCAN_CH 64
__global__ __launch_bounds__(256) void scan_kernel(
    const float* __restrict__ xb, const float* __restrict__ proj,
    const float* __restrict__ par, u16* __restrict__ y) {
    const int b = blockIdx.y;
    const int dblk = blockIdx.x;
    const int tid = threadIdx.x;
    const int lane = tid & 63, wave = tid >> 6;
    const int n = lane & 15;
    const int dl = wave * 4 + (lane >> 4);
    const int d = dblk * 16 + dl;

    const float Aneg = -__expf(par[P_ALOG + d * 16 + n]);
    const float dtw = par[P_DTW + d];
    const float dtb = par[P_DTB + d];
    const float Dp = par[P_DPAR + d];

    __shared__ float sproj[SCAN_CH][33];
    __shared__ float sxb[SCAN_CH][16];

    float h = 0.f;
    const size_t rowbase = (size_t)b * 1024;

    for (int l0 = 0; l0 < 1024; l0 += SCAN_CH) {
        __syncthreads();
        for (int f = tid; f < SCAN_CH * 33; f += 256) {
            const int i = f / 33, j = f - i * 33;
            sproj[i][j] = proj[(rowbase + l0 + i) * 33 + j];
        }
        for (int f = tid; f < SCAN_CH * 16; f += 256) {
            const int i = f >> 4, j = f & 15;
            sxb[i][j] = xb[(rowbase + l0 + i) * 2048 + dblk * 16 + j];
        }
        __syncthreads();
        for (int i = 0; i < SCAN_CH; ++i) {
            const float dtin = sproj[i][0];
            const float Bv = sproj[i][1 + n];
            const float Cv = sproj[i][17 + n];
            const float xv = sxb[i][dl];
            const float darg = fmaf(dtin, dtw, dtb);
            const float dt = (darg > 20.f) ? darg : __logf(1.f + __expf(darg));
            const float dA = __expf(dt * Aneg);
            h = fmaf(dA, h, xv * dt * Bv);
            float yp = h * Cv;
            yp += __shfl_xor(yp, 1);
            yp += __shfl_xor(yp, 2);
            yp += __shfl_xor(yp, 4);
            yp += __shfl_xor(yp, 8);
            if (n == 0)
                y[(rowbase + l0 + i) * 2048 + d] = f2bf(fmaf(xv, Dp, yp));
        }
    }
}

// ---------------------------------------------------------------------------
// LayerNorm over D_INNER + *silu(z); y bf16 in, yn bf16 out.
// ---------------------------------------------------------------------------
__global__ __launch_bounds__(256) void ln_silu(const u16* __restrict__ y,
                                               const u16* __restrict__ xz,
                                               const float* __restrict__ par,
                                               u16* __restrict__ yn) {
    const int row = blockIdx.x;
    const int tid = threadIdx.x;
    const int lane = tid & 63, wave = tid >> 6;
    float v[8];
    float s = 0.f, s2 = 0.f;
#pragma unroll
    for (int i = 0; i < 8; ++i) {
        v[i] = bf2f(y[(size_t)row * 2048 + tid + i * 256]);
        s += v[i];
        s2 = fmaf(v[i], v[i], s2);
    }
    s += __shfl_xor(s, 1); s2 += __shfl_xor(s2, 1);
    s += __shfl_xor(s, 2); s2 += __shfl_xor(s2, 2);
    s += __shfl_xor(s, 4); s2 += __shfl_xor(s2, 4);
    s += __shfl_xor(s, 8); s2 += __shfl_xor(s2, 8);
    s += __shfl_xor(s, 16); s2 += __shfl_xor(s2, 16);
    s += __shfl_xor(s, 32); s2 += __shfl_xor(s2, 32);
    __shared__ float rs[4], rs2[4];
    if (lane == 0) { rs[wave] = s; rs2[wave] = s2; }
    __syncthreads();
    const float ts = rs[0] + rs[1] + rs[2] + rs[3];
    const float ts2 = rs2[0] + rs2[1] + rs2[2] + rs2[3];
    const float mu = ts * (1.f / 2048.f);
    const float var = ts2 * (1.f / 2048.f) - mu * mu;
    const float rstd = rsqrtf(var + 1e-5f);
#pragma unroll
    for (int i = 0; i < 8; ++i) {
        const int d = tid + i * 256;
        float t = (v[i] - mu) * rstd * par[P_LNG + d] + par[P_LNB + d];
        const float z = bf2f(xz[(size_t)row * 4096 + 2048 + d]);
        t *= z / (1.f + __expf(-z));
        yn[(size_t)row * 2048 + d] = f2bf(t);
    }
}

// ---------------------------------------------------------------------------
extern "C" void kernel_launch(void* const* d_in, const int* in_sizes, int n_in,
                              void* d_out, int out_size, void* d_ws, size_t ws_size,
                              hipStream_t stream) {
    const void* x         = d_in[0];   // (2,1024,1024) fp32
    const void* in_proj_w = d_in[1];   // (4096,1024)
    const void* conv_w    = d_in[2];   // (2048,4)
    const void* conv_b    = d_in[3];   // (2048,)
    const void* x_proj_w  = d_in[4];   // (33,2048)
    const void* A_log     = d_in[5];   // (2048,16)
    const void* D_param   = d_in[6];   // (2048,)
    const void* dt_w      = d_in[7];   // (2048,1)
    const void* dt_b      = d_in[8];   // (2048,)
    const void* out_w     = d_in[9];   // (1024,2048)
    const void* ln_g      = d_in[10];  // (2048,)
    const void* ln_b      = d_in[11];  // (2048,)
    const u16* dp = (const u16*)D_param;  // dtype detector (D_param == ones)

    // workspace layout — total ~40.7 MB (proven addressable in r3/r4)
    float* cpar = (float*)d_ws;              // 53,248 f32
    u16* xz     = (u16*)(cpar + P_TOTAL);    // 8,388,608 u16   (16 MB)
    float* xb   = (float*)(xz + 8388608);    // 4,194,304 f32   (16 MB)
    float* proj = xb + 4194304;              // 67,584 f32
    u16* y      = (u16*)(proj + 67584);      // 4,194,304 u16   (8 MB)
    u16* yn     = (u16*)xb;                  // alias xb (dead after scan)

    // 0. canonicalize small params to fp32
    ParamPtrs pp;
    pp.p[0] = conv_w; pp.p[1] = conv_b; pp.p[2] = A_log; pp.p[3] = D_param;
    pp.p[4] = dt_w;   pp.p[5] = dt_b;   pp.p[6] = ln_g;  pp.p[7] = ln_b;
    canon_params<<<P_TOTAL / 256, 256, 0, stream>>>(pp, cpar, dp);

    // 1. in_proj: xz = x @ in_proj_w^T   (M=2048, N=4096, K=1024), bf16 out
    gemm_bt<false, false><<<dim3(16, 32), 256, 0, stream>>>(x, in_proj_w, xz, 2048, 4096, 1024, dp);
    // 2. causal conv4 + silu
    conv_silu<<<16384, 256, 0, stream>>>(xz, cpar, xb);
    // 3. x_proj (N=33)
    xproj<<<2048, 256, 0, stream>>>(xb, x_proj_w, proj, dp);
    // 4. selective scan
    scan_kernel<<<dim3(128, 2), 256, 0, stream>>>(xb, proj, cpar, y);
    // 5. layernorm + silu(z) gate
    ln_silu<<<2048, 256, 0, stream>>>(y, xz, cpar, yn);
    // 6. out proj: out = yn @ out_w^T   (M=2048, N=1024, K=2048), FP32 out
    gemm_bt<true, true><<<dim3(16, 8), 256, 0, stream>>>(yn, out_w, d_out, 2048, 1024, 2048, dp);
}

// Round 6
// 414.467 us; speedup vs baseline: 1.7355x; 1.7355x over previous
//
#include <hip/hip_runtime.h>

typedef unsigned short u16;
typedef unsigned int u32;
typedef __bf16 bf16x8 __attribute__((ext_vector_type(8)));
typedef float f32x4 __attribute__((ext_vector_type(4)));

__device__ __forceinline__ float bf2f(u16 b) {
    return __uint_as_float(((u32)b) << 16);
}
__device__ __forceinline__ u16 f2bf(float f) {
    u32 u = __float_as_uint(f);
    return (u16)((u + 0x7fffu + ((u >> 16) & 1u)) >> 16);
}

// fp32 canonical param block (element offsets)
#define P_CONVW 0       // 2048*4
#define P_CONVB 8192    // 2048
#define P_ALOG  10240   // 2048*16
#define P_DPAR  43008   // 2048
#define P_DTW   45056   // 2048
#define P_DTB   47104   // 2048
#define P_LNG   49152   // 2048
#define P_LNB   51200   // 2048
#define P_TOTAL 53248

// scan chunking
#define CCH 16          // chunks over L=1024
#define CT  64          // timesteps per chunk
#define CHUNKTOT 1048576  // B*CCH*16*2048

struct ParamPtrs { const void* p[8]; };

__global__ __launch_bounds__(256) void canon_params(ParamPtrs pp, float* __restrict__ dst,
                                                    const u16* __restrict__ dp) {
    const bool isbf = (dp[0] != 0);
    const int i = blockIdx.x * 256 + threadIdx.x;  // exact grid over P_TOTAL
    int seg, off;
    if (i < P_CONVB)      { seg = 0; off = i; }
    else if (i < P_ALOG)  { seg = 1; off = i - P_CONVB; }
    else if (i < P_DPAR)  { seg = 2; off = i - P_ALOG; }
    else if (i < P_DTW)   { seg = 3; off = i - P_DPAR; }
    else if (i < P_DTB)   { seg = 4; off = i - P_DTW; }
    else if (i < P_LNG)   { seg = 5; off = i - P_DTB; }
    else if (i < P_LNB)   { seg = 6; off = i - P_LNG; }
    else                  { seg = 7; off = i - P_LNB; }
    dst[i] = isbf ? bf2f(((const u16*)pp.p[seg])[off]) : ((const float*)pp.p[seg])[off];
}

// elementwise convert (or copy) to bf16, 4 elems/thread
__global__ __launch_bounds__(256) void canon_to_bf16(const void* __restrict__ src,
                                                     u16* __restrict__ dst, int n4,
                                                     const u16* __restrict__ dp) {
    const bool isbf = (dp[0] != 0);
    const int i = blockIdx.x * 256 + threadIdx.x;
    if (i >= n4) return;
    if (isbf) {
        ((uint2*)dst)[i] = ((const uint2*)src)[i];
    } else {
        const float4 v = ((const float4*)src)[i];
        uint2 o;
        o.x = (u32)f2bf(v.x) | ((u32)f2bf(v.y) << 16);
        o.y = (u32)f2bf(v.z) | ((u32)f2bf(v.w) << 16);
        ((uint2*)dst)[i] = o;
    }
}

// ---------------------------------------------------------------------------
// GEMM: C[M,N] = A[M,K] (bf16) * W[N,K]^T (bf16).  STORE_F32: fp32 C else bf16.
// 128x128 tile, 4 waves (2x2), 4x4 frags of 16x16, MFMA 16x16x32 bf16.
// ---------------------------------------------------------------------------
template <bool STORE_F32>
__global__ __launch_bounds__(256) void gemm_bt(const u16* __restrict__ A,
                                               const u16* __restrict__ Bw,
                                               void* __restrict__ C,
                                               int M, int N, int K) {
    const int bm = blockIdx.x;
    const int bn = blockIdx.y;
    const int tid = threadIdx.x;
    const int lane = tid & 63;
    const int wave = tid >> 6;
    const int wm = wave >> 1, wn = wave & 1;
    const int l16 = lane & 15, quad = lane >> 4;

    __shared__ __align__(16) u16 sA[128 * 40];
    __shared__ __align__(16) u16 sB[128 * 40];

    f32x4 acc[4][4] = {};

    const int r0 = tid >> 2, c0 = tid & 3;
    const int r1 = r0 + 64;

    for (int k0 = 0; k0 < K; k0 += 32) {
        const uint4 a0 = *(const uint4*)&A[(size_t)(bm * 128 + r0) * K + k0 + c0 * 8];
        const uint4 a1 = *(const uint4*)&A[(size_t)(bm * 128 + r1) * K + k0 + c0 * 8];
        const uint4 b0 = *(const uint4*)&Bw[(size_t)(bn * 128 + r0) * K + k0 + c0 * 8];
        const uint4 b1 = *(const uint4*)&Bw[(size_t)(bn * 128 + r1) * K + k0 + c0 * 8];
        __syncthreads();
        *(uint4*)&sA[r0 * 40 + c0 * 8] = a0;
        *(uint4*)&sA[r1 * 40 + c0 * 8] = a1;
        *(uint4*)&sB[r0 * 40 + c0 * 8] = b0;
        *(uint4*)&sB[r1 * 40 + c0 * 8] = b1;
        __syncthreads();

        bf16x8 af[4], bg[4];
#pragma unroll
        for (int t = 0; t < 4; ++t) {
            af[t] = *(const bf16x8*)&sA[(wm * 64 + t * 16 + l16) * 40 + quad * 8];
            bg[t] = *(const bf16x8*)&sB[(wn * 64 + t * 16 + l16) * 40 + quad * 8];
        }
#pragma unroll
        for (int mt = 0; mt < 4; ++mt)
#pragma unroll
            for (int nt = 0; nt < 4; ++nt)
                acc[mt][nt] = __builtin_amdgcn_mfma_f32_16x16x32_bf16(
                    af[mt], bg[nt], acc[mt][nt], 0, 0, 0);
    }

#pragma unroll
    for (int mt = 0; mt < 4; ++mt) {
#pragma unroll
        for (int r = 0; r < 4; ++r) {
            const int row = bm * 128 + wm * 64 + mt * 16 + quad * 4 + r;
#pragma unroll
            for (int nt = 0; nt < 4; ++nt) {
                const int col = bn * 128 + wn * 64 + nt * 16 + l16;
                if (STORE_F32)
                    ((float*)C)[(size_t)row * N + col] = acc[mt][nt][r];
                else
                    ((u16*)C)[(size_t)row * N + col] = f2bf(acc[mt][nt][r]);
            }
        }
    }
}

// ---------------------------------------------------------------------------
// Depthwise causal conv (D_CONV=4) + SiLU.  xz bf16 (B*L, 4096) -> xb fp32.
// ---------------------------------------------------------------------------
__global__ __launch_bounds__(256) void conv_silu(const u16* __restrict__ xz,
                                                 const float* __restrict__ par,
                                                 float* __restrict__ xb) {
    const int idx = blockIdx.x * 256 + threadIdx.x;  // over 2*1024*2048
    const int d = idx & 2047;
    const int bl = idx >> 11;
    const int l = bl & 1023;
    float acc = par[P_CONVB + d];
#pragma unroll
    for (int k = 0; k < 4; ++k) {
        const int ls = l + k - 3;
        if (ls >= 0)
            acc = fmaf(bf2f(xz[(size_t)(bl + (ls - l)) * 4096 + d]),
                       par[P_CONVW + d * 4 + k], acc);
    }
    xb[idx] = acc / (1.f + __expf(-acc));
}

// ---------------------------------------------------------------------------
// x_proj: proj[row, e] = sum_d xb[row, d] * w[e, d],  e in [0,33), K=2048.
// ---------------------------------------------------------------------------
__global__ __launch_bounds__(256) void xproj(const float* __restrict__ xb,
                                             const void* __restrict__ w,
                                             float* __restrict__ proj,
                                             const u16* __restrict__ dp) {
    const bool isbf = (dp[0] != 0);
    const u16* w16 = (const u16*)w;
    const float* w32 = (const float*)w;
    const int row = blockIdx.x;
    const int tid = threadIdx.x;
    const int lane = tid & 63, wave = tid >> 6;
    float acc[33];
#pragma unroll
    for (int e = 0; e < 33; ++e) acc[e] = 0.f;
#pragma unroll
    for (int i = 0; i < 8; ++i) {
        const int d = tid + i * 256;
        const float xv = xb[(size_t)row * 2048 + d];
#pragma unroll
        for (int e = 0; e < 33; ++e) {
            const float wv = isbf ? bf2f(w16[e * 2048 + d]) : w32[e * 2048 + d];
            acc[e] = fmaf(xv, wv, acc[e]);
        }
    }
    __shared__ float red[4][33];
#pragma unroll
    for (int e = 0; e < 33; ++e) {
        float v = acc[e];
        v += __shfl_xor(v, 1);
        v += __shfl_xor(v, 2);
        v += __shfl_xor(v, 4);
        v += __shfl_xor(v, 8);
        v += __shfl_xor(v, 16);
        v += __shfl_xor(v, 32);
        acc[e] = v;
    }
    if (lane == 0) {
#pragma unroll
        for (int e = 0; e < 33; ++e) red[wave][e] = acc[e];
    }
    __syncthreads();
    if (tid < 33) {
        proj[(size_t)row * 33 + tid] =
            red[0][tid] + red[1][tid] + red[2][tid] + red[3][tid];
    }
}

// ---------------------------------------------------------------------------
// Chunked parallel scan, pass 1: per (b, d, chunk) compute per-n
// P = prod(dA) and S = chunk-local h (starting from 0).  16 n in registers.
// ---------------------------------------------------------------------------
__global__ __launch_bounds__(256) void scan_p1(const float* __restrict__ xb,
                                               const float* __restrict__ proj,
                                               const float* __restrict__ par,
                                               float* __restrict__ PS) {
    const int d = blockIdx.x * 256 + threadIdx.x;   // grid.x = 8
    const int c = blockIdx.y;                       // 0..15
    const int b = blockIdx.z;                       // 0..1
    __shared__ float sp[CT][33];
    const size_t row0 = (size_t)b * 1024 + c * CT;
    for (int f = threadIdx.x; f < CT * 33; f += 256) {
        const int i = f / 33, j = f - i * 33;
        sp[i][j] = proj[(row0 + i) * 33 + j];
    }
    float Aneg[16];
#pragma unroll
    for (int n = 0; n < 16; ++n) Aneg[n] = -__expf(par[P_ALOG + d * 16 + n]);
    const float dtw = par[P_DTW + d], dtb = par[P_DTB + d];
    __syncthreads();

    float h[16] = {}, P[16];
#pragma unroll
    for (int n = 0; n < 16; ++n) P[n] = 1.f;

    float xv = xb[row0 * 2048 + d];
    for (int i = 0; i < CT; ++i) {
        const float xv_next = (i + 1 < CT) ? xb[(row0 + i + 1) * 2048 + d] : 0.f;
        const float dtin = sp[i][0];
        const float darg = fmaf(dtin, dtw, dtb);
        const float dt = (darg > 20.f) ? darg : __logf(1.f + __expf(darg));
        const float xdt = xv * dt;
#pragma unroll
        for (int n = 0; n < 16; ++n) {
            const float dA = __expf(dt * Aneg[n]);
            P[n] *= dA;
            h[n] = fmaf(dA, h[n], xdt * sp[i][1 + n]);
        }
        xv = xv_next;
    }
    const size_t base = (((size_t)b * CCH + c) * 16) * 2048 + d;
#pragma unroll
    for (int n = 0; n < 16; ++n) {
        PS[base + (size_t)n * 2048] = P[n];
        PS[CHUNKTOT + base + (size_t)n * 2048] = h[n];
    }
}

// ---------------------------------------------------------------------------
// Combine: per (b,d,n), serial scan over 16 chunks: H_c = state before chunk c.
// ---------------------------------------------------------------------------
__global__ __launch_bounds__(256) void scan_comb(const float* __restrict__ PS,
                                                 float* __restrict__ H) {
    const int t = blockIdx.x * 256 + threadIdx.x;  // 65536 total
    const int d = t & 2047;
    const int n = (t >> 11) & 15;
    const int b = t >> 15;
    float h = 0.f;
#pragma unroll
    for (int c = 0; c < CCH; ++c) {
        const size_t idx = (((size_t)b * CCH + c) * 16 + n) * 2048 + d;
        H[idx] = h;
        h = fmaf(PS[idx], h, PS[CHUNKTOT + idx]);
    }
}

// ---------------------------------------------------------------------------
// Pass 2: replay each chunk from its true initial state H_c, emit y (bf16).
// ---------------------------------------------------------------------------
__global__ __launch_bounds__(256) void scan_p2(const float* __restrict__ xb,
                                               const float* __restrict__ proj,
                                               const float* __restrict__ par,
                                               const float* __restrict__ H,
                                               u16* __restrict__ y) {
    const int d = blockIdx.x * 256 + threadIdx.x;
    const int c = blockIdx.y;
    const int b = blockIdx.z;
    __shared__ float sp[CT][33];
    const size_t row0 = (size_t)b * 1024 + c * CT;
    for (int f = threadIdx.x; f < CT * 33; f += 256) {
        const int i = f / 33, j = f - i * 33;
        sp[i][j] = proj[(row0 + i) * 33 + j];
    }
    float Aneg[16], h[16];
    const size_t hbase = (((size_t)b * CCH + c) * 16) * 2048 + d;
#pragma unroll
    for (int n = 0; n < 16; ++n) {
        Aneg[n] = -__expf(par[P_ALOG + d * 16 + n]);
        h[n] = H[hbase + (size_t)n * 2048];
    }
    const float dtw = par[P_DTW + d], dtb = par[P_DTB + d];
    const float Dp = par[P_DPAR + d];
    __syncthreads();

    float xv = xb[row0 * 2048 + d];
    for (int i = 0; i < CT; ++i) {
        const float xv_next = (i + 1 < CT) ? xb[(row0 + i + 1) * 2048 + d] : 0.f;
        const float dtin = sp[i][0];
        const float darg = fmaf(dtin, dtw, dtb);
        const float dt = (darg > 20.f) ? darg : __logf(1.f + __expf(darg));
        const float xdt = xv * dt;
        float acc = 0.f;
#pragma unroll
        for (int n = 0; n < 16; ++n) {
            const float dA = __expf(dt * Aneg[n]);
            h[n] = fmaf(dA, h[n], xdt * sp[i][1 + n]);
            acc = fmaf(h[n], sp[i][17 + n], acc);
        }
        y[(row0 + i) * 2048 + d] = f2bf(fmaf(xv, Dp, acc));
        xv = xv_next;
    }
}

// ---------------------------------------------------------------------------
// LayerNorm over D_INNER + *silu(z); y bf16 in, yn bf16 out.
// ---------------------------------------------------------------------------
__global__ __launch_bounds__(256) void ln_silu(const u16* __restrict__ y,
                                               const u16* __restrict__ xz,
                                               const float* __restrict__ par,
                                               u16* __restrict__ yn) {
    const int row = blockIdx.x;
    const int tid = threadIdx.x;
    const int lane = tid & 63, wave = tid >> 6;
    float v[8];
    float s = 0.f, s2 = 0.f;
#pragma unroll
    for (int i = 0; i < 8; ++i) {
        v[i] = bf2f(y[(size_t)row * 2048 + tid + i * 256]);
        s += v[i];
        s2 = fmaf(v[i], v[i], s2);
    }
    s += __shfl_xor(s, 1); s2 += __shfl_xor(s2, 1);
    s += __shfl_xor(s, 2); s2 += __shfl_xor(s2, 2);
    s += __shfl_xor(s, 4); s2 += __shfl_xor(s2, 4);
    s += __shfl_xor(s, 8); s2 += __shfl_xor(s2, 8);
    s += __shfl_xor(s, 16); s2 += __shfl_xor(s2, 16);
    s += __shfl_xor(s, 32); s2 += __shfl_xor(s2, 32);
    __shared__ float rs[4], rs2[4];
    if (lane == 0) { rs[wave] = s; rs2[wave] = s2; }
    __syncthreads();
    const float ts = rs[0] + rs[1] + rs[2] + rs[3];
    const float ts2 = rs2[0] + rs2[1] + rs2[2] + rs2[3];
    const float mu = ts * (1.f / 2048.f);
    const float var = ts2 * (1.f / 2048.f) - mu * mu;
    const float rstd = rsqrtf(var + 1e-5f);
#pragma unroll
    for (int i = 0; i < 8; ++i) {
        const int d = tid + i * 256;
        float t = (v[i] - mu) * rstd * par[P_LNG + d] + par[P_LNB + d];
        const float z = bf2f(xz[(size_t)row * 4096 + 2048 + d]);
        t *= z / (1.f + __expf(-z));
        yn[(size_t)row * 2048 + d] = f2bf(t);
    }
}

// ---------------------------------------------------------------------------
extern "C" void kernel_launch(void* const* d_in, const int* in_sizes, int n_in,
                              void* d_out, int out_size, void* d_ws, size_t ws_size,
                              hipStream_t stream) {
    const void* x         = d_in[0];   // (2,1024,1024) fp32
    const void* in_proj_w = d_in[1];
    const void* conv_w    = d_in[2];
    const void* conv_b    = d_in[3];
    const void* x_proj_w  = d_in[4];
    const void* A_log     = d_in[5];
    const void* D_param   = d_in[6];
    const void* dt_w      = d_in[7];
    const void* dt_b      = d_in[8];
    const void* out_w     = d_in[9];
    const void* ln_g      = d_in[10];
    const void* ln_b      = d_in[11];
    const u16* dp = (const u16*)D_param;

    // workspace layout — 56.5 MB total
    float* cpar = (float*)d_ws;              // 53,248 f32
    u16* cx     = (u16*)(cpar + P_TOTAL);    // 2,097,152 u16 (4 MB)
    u16* cw1    = cx + 2097152;              // 4,194,304 u16 (8 MB)
    u16* cwo    = cw1 + 4194304;             // 2,097,152 u16 (4 MB)
    u16* xz     = cwo + 2097152;             // 8,388,608 u16 (16 MB)
    float* xb   = (float*)(xz + 8388608);    // 4,194,304 f32 (16 MB)
    float* proj = xb + 4194304;              // 67,584 f32
    u16* y      = (u16*)(proj + 67584);      // 4,194,304 u16 (8 MB)
    // overlays: PS (8 MB) + H (4 MB) reuse cx+cw1 (dead after gemm1)
    float* PS   = (float*)cx;                // 2*CHUNKTOT f32
    float* H    = (float*)cx + 2 * CHUNKTOT; // CHUNKTOT f32
    u16* yn     = (u16*)xb;                  // alias xb (dead after scan_p2)

    // 0. canonicalize params + convert GEMM operands to bf16
    ParamPtrs pp;
    pp.p[0] = conv_w; pp.p[1] = conv_b; pp.p[2] = A_log; pp.p[3] = D_param;
    pp.p[4] = dt_w;   pp.p[5] = dt_b;   pp.p[6] = ln_g;  pp.p[7] = ln_b;
    canon_params<<<P_TOTAL / 256, 256, 0, stream>>>(pp, cpar, dp);
    canon_to_bf16<<<2048, 256, 0, stream>>>(x, cx, 524288, dp);
    canon_to_bf16<<<4096, 256, 0, stream>>>(in_proj_w, cw1, 1048576, dp);
    canon_to_bf16<<<2048, 256, 0, stream>>>(out_w, cwo, 524288, dp);

    // 1. in_proj: xz = x @ in_proj_w^T   (M=2048, N=4096, K=1024), bf16 out
    gemm_bt<false><<<dim3(16, 32), 256, 0, stream>>>(cx, cw1, xz, 2048, 4096, 1024);
    // 2. causal conv4 + silu
    conv_silu<<<16384, 256, 0, stream>>>(xz, cpar, xb);
    // 3. x_proj (N=33)
    xproj<<<2048, 256, 0, stream>>>(xb, x_proj_w, proj, dp);
    // 4. chunked parallel scan (PS/H overlay cx/cw1 — dead after gemm1)
    scan_p1<<<dim3(8, CCH, 2), 256, 0, stream>>>(xb, proj, cpar, PS);
    scan_comb<<<256, 256, 0, stream>>>(PS, H);
    scan_p2<<<dim3(8, CCH, 2), 256, 0, stream>>>(xb, proj, cpar, H, y);
    // 5. layernorm + silu(z) gate
    ln_silu<<<2048, 256, 0, stream>>>(y, xz, cpar, yn);
    // 6. out proj: out = yn @ out_w^T   (M=2048, N=1024, K=2048), fp32 out
    gemm_bt<true><<<dim3(16, 8), 256, 0, stream>>>(yn, cwo, d_out, 2048, 1024, 2048);
}

// Round 7
// 339.163 us; speedup vs baseline: 2.1209x; 1.2220x over previous
//
#include <hip/hip_runtime.h>

typedef unsigned short u16;
typedef unsigned int u32;
typedef __bf16 bf16x8 __attribute__((ext_vector_type(8)));
typedef float f32x4 __attribute__((ext_vector_type(4)));

__device__ __forceinline__ float bf2f(u16 b) {
    return __uint_as_float(((u32)b) << 16);
}
__device__ __forceinline__ u16 f2bf(float f) {
    u32 u = __float_as_uint(f);
    return (u16)((u + 0x7fffu + ((u >> 16) & 1u)) >> 16);
}

// fp32 canonical param block (element offsets)
#define P_CONVW 0       // 2048*4
#define P_CONVB 8192    // 2048
#define P_ALOG  10240   // 2048*16
#define P_DPAR  43008   // 2048
#define P_DTW   45056   // 2048
#define P_DTB   47104   // 2048
#define P_LNG   49152   // 2048
#define P_LNB   51200   // 2048
#define P_TOTAL 53248

// scan chunking
#define CCH 16            // chunks over L=1024
#define CT  64            // timesteps per chunk
#define CHUNKTOT 1048576  // B*CCH*16*2048
#define PSTRIDE 128       // proj row stride (N padded for MFMA)

struct ParamPtrs { const void* p[8]; };

__global__ __launch_bounds__(256) void canon_params(ParamPtrs pp, float* __restrict__ dst,
                                                    const u16* __restrict__ dp) {
    const bool isbf = (dp[0] != 0);
    const int i = blockIdx.x * 256 + threadIdx.x;  // exact grid over P_TOTAL
    int seg, off;
    if (i < P_CONVB)      { seg = 0; off = i; }
    else if (i < P_ALOG)  { seg = 1; off = i - P_CONVB; }
    else if (i < P_DPAR)  { seg = 2; off = i - P_ALOG; }
    else if (i < P_DTW)   { seg = 3; off = i - P_DPAR; }
    else if (i < P_DTB)   { seg = 4; off = i - P_DTW; }
    else if (i < P_LNG)   { seg = 5; off = i - P_DTB; }
    else if (i < P_LNB)   { seg = 6; off = i - P_LNG; }
    else                  { seg = 7; off = i - P_LNB; }
    dst[i] = isbf ? bf2f(((const u16*)pp.p[seg])[off]) : ((const float*)pp.p[seg])[off];
}

// elementwise convert (or copy) to bf16, 4 elems/thread
__global__ __launch_bounds__(256) void canon_to_bf16(const void* __restrict__ src,
                                                     u16* __restrict__ dst, int n4,
                                                     const u16* __restrict__ dp) {
    const bool isbf = (dp[0] != 0);
    const int i = blockIdx.x * 256 + threadIdx.x;
    if (i >= n4) return;
    if (isbf) {
        ((uint2*)dst)[i] = ((const uint2*)src)[i];
    } else {
        const float4 v = ((const float4*)src)[i];
        uint2 o;
        o.x = (u32)f2bf(v.x) | ((u32)f2bf(v.y) << 16);
        o.y = (u32)f2bf(v.z) | ((u32)f2bf(v.w) << 16);
        ((uint2*)dst)[i] = o;
    }
}

// x_proj_w (33,2048) -> zero-padded bf16 (128,2048)
__global__ __launch_bounds__(256) void canon_wpad(const void* __restrict__ src,
                                                  u16* __restrict__ dst,
                                                  const u16* __restrict__ dp) {
    const bool isbf = (dp[0] != 0);
    const int i = blockIdx.x * 256 + threadIdx.x;  // over 128*2048/4 = 65536
    const int idx = i * 4;
    const int row = idx >> 11;
    u16 o[4];
#pragma unroll
    for (int q = 0; q < 4; ++q) {
        float v = 0.f;
        if (row < 33)
            v = isbf ? bf2f(((const u16*)src)[idx + q]) : ((const float*)src)[idx + q];
        o[q] = f2bf(v);
    }
    *(uint2*)&dst[idx] = *(uint2*)o;
}

// ---------------------------------------------------------------------------
// GEMM: C[M,N] = A[M,K] (bf16) * W[N,K]^T (bf16).  STORE_F32: fp32 C else bf16.
// 128x128 tile, 4 waves (2x2), 4x4 frags of 16x16, MFMA 16x16x32 bf16.
// ---------------------------------------------------------------------------
template <bool STORE_F32>
__global__ __launch_bounds__(256) void gemm_bt(const u16* __restrict__ A,
                                               const u16* __restrict__ Bw,
                                               void* __restrict__ C,
                                               int M, int N, int K) {
    const int bm = blockIdx.x;
    const int bn = blockIdx.y;
    const int tid = threadIdx.x;
    const int lane = tid & 63;
    const int wave = tid >> 6;
    const int wm = wave >> 1, wn = wave & 1;
    const int l16 = lane & 15, quad = lane >> 4;

    __shared__ __align__(16) u16 sA[128 * 40];
    __shared__ __align__(16) u16 sB[128 * 40];

    f32x4 acc[4][4] = {};

    const int r0 = tid >> 2, c0 = tid & 3;
    const int r1 = r0 + 64;

    for (int k0 = 0; k0 < K; k0 += 32) {
        const uint4 a0 = *(const uint4*)&A[(size_t)(bm * 128 + r0) * K + k0 + c0 * 8];
        const uint4 a1 = *(const uint4*)&A[(size_t)(bm * 128 + r1) * K + k0 + c0 * 8];
        const uint4 b0 = *(const uint4*)&Bw[(size_t)(bn * 128 + r0) * K + k0 + c0 * 8];
        const uint4 b1 = *(const uint4*)&Bw[(size_t)(bn * 128 + r1) * K + k0 + c0 * 8];
        __syncthreads();
        *(uint4*)&sA[r0 * 40 + c0 * 8] = a0;
        *(uint4*)&sA[r1 * 40 + c0 * 8] = a1;
        *(uint4*)&sB[r0 * 40 + c0 * 8] = b0;
        *(uint4*)&sB[r1 * 40 + c0 * 8] = b1;
        __syncthreads();

        bf16x8 af[4], bg[4];
#pragma unroll
        for (int t = 0; t < 4; ++t) {
            af[t] = *(const bf16x8*)&sA[(wm * 64 + t * 16 + l16) * 40 + quad * 8];
            bg[t] = *(const bf16x8*)&sB[(wn * 64 + t * 16 + l16) * 40 + quad * 8];
        }
#pragma unroll
        for (int mt = 0; mt < 4; ++mt)
#pragma unroll
            for (int nt = 0; nt < 4; ++nt)
                acc[mt][nt] = __builtin_amdgcn_mfma_f32_16x16x32_bf16(
                    af[mt], bg[nt], acc[mt][nt], 0, 0, 0);
    }

#pragma unroll
    for (int mt = 0; mt < 4; ++mt) {
#pragma unroll
        for (int r = 0; r < 4; ++r) {
            const int row = bm * 128 + wm * 64 + mt * 16 + quad * 4 + r;
#pragma unroll
            for (int nt = 0; nt < 4; ++nt) {
                const int col = bn * 128 + wn * 64 + nt * 16 + l16;
                if (STORE_F32)
                    ((float*)C)[(size_t)row * N + col] = acc[mt][nt][r];
                else
                    ((u16*)C)[(size_t)row * N + col] = f2bf(acc[mt][nt][r]);
            }
        }
    }
}

// ---------------------------------------------------------------------------
// Depthwise causal conv (D_CONV=4) + SiLU.  xz bf16 (B*L, 4096) -> xb fp32
// and xb16 bf16 (for the x_proj MFMA GEMM).
// ---------------------------------------------------------------------------
__global__ __launch_bounds__(256) void conv_silu(const u16* __restrict__ xz,
                                                 const float* __restrict__ par,
                                                 float* __restrict__ xb,
                                                 u16* __restrict__ xb16) {
    const int idx = blockIdx.x * 256 + threadIdx.x;  // over 2*1024*2048
    const int d = idx & 2047;
    const int bl = idx >> 11;
    const int l = bl & 1023;
    float acc = par[P_CONVB + d];
#pragma unroll
    for (int k = 0; k < 4; ++k) {
        const int ls = l + k - 3;
        if (ls >= 0)
            acc = fmaf(bf2f(xz[(size_t)(bl + (ls - l)) * 4096 + d]),
                       par[P_CONVW + d * 4 + k], acc);
    }
    const float s = acc / (1.f + __expf(-acc));
    xb[idx] = s;
    xb16[idx] = f2bf(s);
}

// ---------------------------------------------------------------------------
// Chunked parallel scan, pass 1: per (b, d, chunk) compute per-n
// P = prod(dA) and S = chunk-local h (starting from 0).  16 n in registers.
// ---------------------------------------------------------------------------
__global__ __launch_bounds__(256) void scan_p1(const float* __restrict__ xb,
                                               const float* __restrict__ proj,
                                               const float* __restrict__ par,
                                               float* __restrict__ PS) {
    const int d = blockIdx.x * 256 + threadIdx.x;   // grid.x = 8
    const int c = blockIdx.y;                       // 0..15
    const int b = blockIdx.z;                       // 0..1
    __shared__ float sp[CT][33];
    const size_t row0 = (size_t)b * 1024 + c * CT;
    for (int f = threadIdx.x; f < CT * 33; f += 256) {
        const int i = f / 33, j = f - i * 33;
        sp[i][j] = proj[(row0 + i) * PSTRIDE + j];
    }
    float Aneg[16];
#pragma unroll
    for (int n = 0; n < 16; ++n) Aneg[n] = -__expf(par[P_ALOG + d * 16 + n]);
    const float dtw = par[P_DTW + d], dtb = par[P_DTB + d];
    __syncthreads();

    float h[16] = {}, P[16];
#pragma unroll
    for (int n = 0; n < 16; ++n) P[n] = 1.f;

    float xv = xb[row0 * 2048 + d];
    for (int i = 0; i < CT; ++i) {
        const float xv_next = (i + 1 < CT) ? xb[(row0 + i + 1) * 2048 + d] : 0.f;
        const float dtin = sp[i][0];
        const float darg = fmaf(dtin, dtw, dtb);
        const float dt = (darg > 20.f) ? darg : __logf(1.f + __expf(darg));
        const float xdt = xv * dt;
#pragma unroll
        for (int n = 0; n < 16; ++n) {
            const float dA = __expf(dt * Aneg[n]);
            P[n] *= dA;
            h[n] = fmaf(dA, h[n], xdt * sp[i][1 + n]);
        }
        xv = xv_next;
    }
    const size_t base = (((size_t)b * CCH + c) * 16) * 2048 + d;
#pragma unroll
    for (int n = 0; n < 16; ++n) {
        PS[base + (size_t)n * 2048] = P[n];
        PS[CHUNKTOT + base + (size_t)n * 2048] = h[n];
    }
}

// ---------------------------------------------------------------------------
// Combine: per (b,d,n), serial scan over 16 chunks: H_c = state before chunk c.
// ---------------------------------------------------------------------------
__global__ __launch_bounds__(256) void scan_comb(const float* __restrict__ PS,
                                                 float* __restrict__ H) {
    const int t = blockIdx.x * 256 + threadIdx.x;  // 65536 total
    const int d = t & 2047;
    const int n = (t >> 11) & 15;
    const int b = t >> 15;
    float h = 0.f;
#pragma unroll
    for (int c = 0; c < CCH; ++c) {
        const size_t idx = (((size_t)b * CCH + c) * 16 + n) * 2048 + d;
        H[idx] = h;
        h = fmaf(PS[idx], h, PS[CHUNKTOT + idx]);
    }
}

// ---------------------------------------------------------------------------
// Pass 2: replay each chunk from its true initial state H_c, emit y (bf16).
// ---------------------------------------------------------------------------
__global__ __launch_bounds__(256) void scan_p2(const float* __restrict__ xb,
                                               const float* __restrict__ proj,
                                               const float* __restrict__ par,
                                               const float* __restrict__ H,
                                               u16* __restrict__ y) {
    const int d = blockIdx.x * 256 + threadIdx.x;
    const int c = blockIdx.y;
    const int b = blockIdx.z;
    __shared__ float sp[CT][33];
    const size_t row0 = (size_t)b * 1024 + c * CT;
    for (int f = threadIdx.x; f < CT * 33; f += 256) {
        const int i = f / 33, j = f - i * 33;
        sp[i][j] = proj[(row0 + i) * PSTRIDE + j];
    }
    float Aneg[16], h[16];
    const size_t hbase = (((size_t)b * CCH + c) * 16) * 2048 + d;
#pragma unroll
    for (int n = 0; n < 16; ++n) {
        Aneg[n] = -__expf(par[P_ALOG + d * 16 + n]);
        h[n] = H[hbase + (size_t)n * 2048];
    }
    const float dtw = par[P_DTW + d], dtb = par[P_DTB + d];
    const float Dp = par[P_DPAR + d];
    __syncthreads();

    float xv = xb[row0 * 2048 + d];
    for (int i = 0; i < CT; ++i) {
        const float xv_next = (i + 1 < CT) ? xb[(row0 + i + 1) * 2048 + d] : 0.f;
        const float dtin = sp[i][0];
        const float darg = fmaf(dtin, dtw, dtb);
        const float dt = (darg > 20.f) ? darg : __logf(1.f + __expf(darg));
        const float xdt = xv * dt;
        float acc = 0.f;
#pragma unroll
        for (int n = 0; n < 16; ++n) {
            const float dA = __expf(dt * Aneg[n]);
            h[n] = fmaf(dA, h[n], xdt * sp[i][1 + n]);
            acc = fmaf(h[n], sp[i][17 + n], acc);
        }
        y[(row0 + i) * 2048 + d] = f2bf(fmaf(xv, Dp, acc));
        xv = xv_next;
    }
}

// ---------------------------------------------------------------------------
// LayerNorm over D_INNER + *silu(z); y bf16 in, yn bf16 out.
// ---------------------------------------------------------------------------
__global__ __launch_bounds__(256) void ln_silu(const u16* __restrict__ y,
                                               const u16* __restrict__ xz,
                                               const float* __restrict__ par,
                                               u16* __restrict__ yn) {
    const int row = blockIdx.x;
    const int tid = threadIdx.x;
    const int lane = tid & 63, wave = tid >> 6;
    float v[8];
    float s = 0.f, s2 = 0.f;
#pragma unroll
    for (int i = 0; i < 8; ++i) {
        v[i] = bf2f(y[(size_t)row * 2048 + tid + i * 256]);
        s += v[i];
        s2 = fmaf(v[i], v[i], s2);
    }
    s += __shfl_xor(s, 1); s2 += __shfl_xor(s2, 1);
    s += __shfl_xor(s, 2); s2 += __shfl_xor(s2, 2);
    s += __shfl_xor(s, 4); s2 += __shfl_xor(s2, 4);
    s += __shfl_xor(s, 8); s2 += __shfl_xor(s2, 8);
    s += __shfl_xor(s, 16); s2 += __shfl_xor(s2, 16);
    s += __shfl_xor(s, 32); s2 += __shfl_xor(s2, 32);
    __shared__ float rs[4], rs2[4];
    if (lane == 0) { rs[wave] = s; rs2[wave] = s2; }
    __syncthreads();
    const float ts = rs[0] + rs[1] + rs[2] + rs[3];
    const float ts2 = rs2[0] + rs2[1] + rs2[2] + rs2[3];
    const float mu = ts * (1.f / 2048.f);
    const float var = ts2 * (1.f / 2048.f) - mu * mu;
    const float rstd = rsqrtf(var + 1e-5f);
#pragma unroll
    for (int i = 0; i < 8; ++i) {
        const int d = tid + i * 256;
        float t = (v[i] - mu) * rstd * par[P_LNG + d] + par[P_LNB + d];
        const float z = bf2f(xz[(size_t)row * 4096 + 2048 + d]);
        t *= z / (1.f + __expf(-z));
        yn[(size_t)row * 2048 + d] = f2bf(t);
    }
}

// ---------------------------------------------------------------------------
extern "C" void kernel_launch(void* const* d_in, const int* in_sizes, int n_in,
                              void* d_out, int out_size, void* d_ws, size_t ws_size,
                              hipStream_t stream) {
    const void* x         = d_in[0];   // (2,1024,1024) fp32
    const void* in_proj_w = d_in[1];
    const void* conv_w    = d_in[2];
    const void* conv_b    = d_in[3];
    const void* x_proj_w  = d_in[4];
    const void* A_log     = d_in[5];
    const void* D_param   = d_in[6];
    const void* dt_w      = d_in[7];
    const void* dt_b      = d_in[8];
    const void* out_w     = d_in[9];
    const void* ln_g      = d_in[10];
    const void* ln_b      = d_in[11];
    const u16* dp = (const u16*)D_param;

    // workspace layout — 65.7 MB total
    float* cpar = (float*)d_ws;              // 53,248 f32
    u16* cx     = (u16*)(cpar + P_TOTAL);    // 2,097,152 u16 (4 MB)
    u16* cw1    = cx + 2097152;              // 4,194,304 u16 (8 MB)
    u16* cwo    = cw1 + 4194304;             // 2,097,152 u16 (4 MB)
    u16* xz     = cwo + 2097152;             // 8,388,608 u16 (16 MB)
    float* xb   = (float*)(xz + 8388608);    // 4,194,304 f32 (16 MB)
    u16* xb16   = (u16*)(xb + 4194304);      // 4,194,304 u16 (8 MB)
    u16* y      = xb16 + 4194304;            // 4,194,304 u16 (8 MB)
    u16* wpad   = y + 4194304;               // 262,144 u16   (0.5 MB)
    float* proj = (float*)(wpad + 262144);   // 2048*128 f32  (1 MB)
    // overlays: PS (8 MB) + H (4 MB) reuse cx+cw1 (dead after gemm1)
    float* PS   = (float*)cx;                // 2*CHUNKTOT f32
    float* H    = (float*)cx + 2 * CHUNKTOT; // CHUNKTOT f32
    u16* yn     = (u16*)xb;                  // alias xb (dead after scan_p2)

    // 0. canonicalize params + convert GEMM operands to bf16
    ParamPtrs pp;
    pp.p[0] = conv_w; pp.p[1] = conv_b; pp.p[2] = A_log; pp.p[3] = D_param;
    pp.p[4] = dt_w;   pp.p[5] = dt_b;   pp.p[6] = ln_g;  pp.p[7] = ln_b;
    canon_params<<<P_TOTAL / 256, 256, 0, stream>>>(pp, cpar, dp);
    canon_to_bf16<<<2048, 256, 0, stream>>>(x, cx, 524288, dp);
    canon_to_bf16<<<4096, 256, 0, stream>>>(in_proj_w, cw1, 1048576, dp);
    canon_to_bf16<<<2048, 256, 0, stream>>>(out_w, cwo, 524288, dp);
    canon_wpad<<<256, 256, 0, stream>>>(x_proj_w, wpad, dp);

    // 1. in_proj: xz = x @ in_proj_w^T   (M=2048, N=4096, K=1024), bf16 out
    gemm_bt<false><<<dim3(16, 32), 256, 0, stream>>>(cx, cw1, xz, 2048, 4096, 1024);
    // 2. causal conv4 + silu (fp32 + bf16 outputs)
    conv_silu<<<16384, 256, 0, stream>>>(xz, cpar, xb, xb16);
    // 3. x_proj as MFMA GEMM: proj = xb16 @ wpad^T (M=2048, N=128, K=2048)
    gemm_bt<true><<<dim3(16, 1), 256, 0, stream>>>(xb16, wpad, proj, 2048, 128, 2048);
    // 4. chunked parallel scan
    scan_p1<<<dim3(8, CCH, 2), 256, 0, stream>>>(xb, proj, cpar, PS);
    scan_comb<<<256, 256, 0, stream>>>(PS, H);
    scan_p2<<<dim3(8, CCH, 2), 256, 0, stream>>>(xb, proj, cpar, H, y);
    // 5. layernorm + silu(z) gate
    ln_silu<<<2048, 256, 0, stream>>>(y, xz, cpar, yn);
    // 6. out proj: out = yn @ out_w^T   (M=2048, N=1024, K=2048), fp32 out
    gemm_bt<true><<<dim3(16, 8), 256, 0, stream>>>(yn, cwo, d_out, 2048, 1024, 2048);
}

// Round 8
// 260.690 us; speedup vs baseline: 2.7593x; 1.3010x over previous
//
#include <hip/hip_runtime.h>

typedef unsigned short u16;
typedef unsigned int u32;
typedef __bf16 bf16x8 __attribute__((ext_vector_type(8)));
typedef float f32x4 __attribute__((ext_vector_type(4)));

__device__ __forceinline__ float bf2f(u16 b) {
    return __uint_as_float(((u32)b) << 16);
}
__device__ __forceinline__ u16 f2bf(float f) {
    u32 u = __float_as_uint(f);
    return (u16)((u + 0x7fffu + ((u >> 16) & 1u)) >> 16);
}

// fp32 canonical param block (element offsets)
#define P_CONVW 0       // 2048*4
#define P_CONVB 8192    // 2048
#define P_ALOG  10240   // 2048*16
#define P_DPAR  43008   // 2048
#define P_DTW   45056   // 2048
#define P_DTB   47104   // 2048
#define P_LNG   49152   // 2048
#define P_LNB   51200   // 2048
#define P_TOTAL 53248

// scan chunking
#define CCH 32            // chunks over L=1024
#define CT  32            // timesteps per chunk
#define CHUNKTOT 2097152  // B*CCH*16*2048
#define PSTRIDE 128       // proj row stride (N padded for MFMA)

struct ParamPtrs { const void* p[8]; };

__global__ __launch_bounds__(256) void canon_params(ParamPtrs pp, float* __restrict__ dst,
                                                    const u16* __restrict__ dp) {
    const bool isbf = (dp[0] != 0);
    const int i = blockIdx.x * 256 + threadIdx.x;  // exact grid over P_TOTAL
    int seg, off;
    if (i < P_CONVB)      { seg = 0; off = i; }
    else if (i < P_ALOG)  { seg = 1; off = i - P_CONVB; }
    else if (i < P_DPAR)  { seg = 2; off = i - P_ALOG; }
    else if (i < P_DTW)   { seg = 3; off = i - P_DPAR; }
    else if (i < P_DTB)   { seg = 4; off = i - P_DTW; }
    else if (i < P_LNG)   { seg = 5; off = i - P_DTB; }
    else if (i < P_LNB)   { seg = 6; off = i - P_LNG; }
    else                  { seg = 7; off = i - P_LNB; }
    dst[i] = isbf ? bf2f(((const u16*)pp.p[seg])[off]) : ((const float*)pp.p[seg])[off];
}

// convert x / in_proj_w / out_w to bf16 into the contiguous cx|cw1|cwo region.
// 4 elems per thread (uint2 dst).  Segment starts in uint2 units.
#define CV_X   524288
#define CV_W1  1572864
#define CV_TOT 2097152
__global__ __launch_bounds__(256) void canon_multi(const void* __restrict__ sx,
                                                   const void* __restrict__ sw1,
                                                   const void* __restrict__ swo,
                                                   u16* __restrict__ dst,
                                                   const u16* __restrict__ dp) {
    const bool isbf = (dp[0] != 0);
    const int i = blockIdx.x * 256 + threadIdx.x;
    if (i >= CV_TOT) return;
    const void* src;
    int off;
    if (i < CV_X)       { src = sx;  off = i; }
    else if (i < CV_W1) { src = sw1; off = i - CV_X; }
    else                { src = swo; off = i - CV_W1; }
    if (isbf) {
        ((uint2*)dst)[i] = ((const uint2*)src)[off];
    } else {
        const float4 v = ((const float4*)src)[off];
        uint2 o;
        o.x = (u32)f2bf(v.x) | ((u32)f2bf(v.y) << 16);
        o.y = (u32)f2bf(v.z) | ((u32)f2bf(v.w) << 16);
        ((uint2*)dst)[i] = o;
    }
}

// x_proj_w (33,2048) -> zero-padded bf16 (128,2048)
__global__ __launch_bounds__(256) void canon_wpad(const void* __restrict__ src,
                                                  u16* __restrict__ dst,
                                                  const u16* __restrict__ dp) {
    const bool isbf = (dp[0] != 0);
    const int i = blockIdx.x * 256 + threadIdx.x;  // over 128*2048/4 = 65536
    const int idx = i * 4;
    const int row = idx >> 11;
    u16 o[4];
#pragma unroll
    for (int q = 0; q < 4; ++q) {
        float v = 0.f;
        if (row < 33)
            v = isbf ? bf2f(((const u16*)src)[idx + q]) : ((const float*)src)[idx + q];
        o[q] = f2bf(v);
    }
    *(uint2*)&dst[idx] = *(uint2*)o;
}

// ---------------------------------------------------------------------------
// GEMM: C[M,N] (+= over z) = A[M, kbase:kbase+Kseg] * W[N, same]^T, bf16 in.
// blockIdx.z selects a K segment; partial written to C + z*M*N (fp32) —
// reduce_parts sums them.  STORE_F32: fp32 C else bf16 C (z==0 only).
// 128x128 tile, 4 waves (2x2), 4x4 frags of 16x16, MFMA 16x16x32 bf16.
// ---------------------------------------------------------------------------
template <bool STORE_F32>
__global__ __launch_bounds__(256) void gemm_bt(const u16* __restrict__ A,
                                               const u16* __restrict__ Bw,
                                               void* __restrict__ C,
                                               int M, int N, int Kseg,
                                               int lda, int ldb) {
    const int bm = blockIdx.x;
    const int bn = blockIdx.y;
    const int kbase = blockIdx.z * Kseg;
    const int tid = threadIdx.x;
    const int lane = tid & 63;
    const int wave = tid >> 6;
    const int wm = wave >> 1, wn = wave & 1;
    const int l16 = lane & 15, quad = lane >> 4;

    __shared__ __align__(16) u16 sA[128 * 40];
    __shared__ __align__(16) u16 sB[128 * 40];

    f32x4 acc[4][4] = {};

    const int r0 = tid >> 2, c0 = tid & 3;
    const int r1 = r0 + 64;

    for (int k0 = 0; k0 < Kseg; k0 += 32) {
        const int kc = kbase + k0 + c0 * 8;
        const uint4 a0 = *(const uint4*)&A[(size_t)(bm * 128 + r0) * lda + kc];
        const uint4 a1 = *(const uint4*)&A[(size_t)(bm * 128 + r1) * lda + kc];
        const uint4 b0 = *(const uint4*)&Bw[(size_t)(bn * 128 + r0) * ldb + kc];
        const uint4 b1 = *(const uint4*)&Bw[(size_t)(bn * 128 + r1) * ldb + kc];
        __syncthreads();
        *(uint4*)&sA[r0 * 40 + c0 * 8] = a0;
        *(uint4*)&sA[r1 * 40 + c0 * 8] = a1;
        *(uint4*)&sB[r0 * 40 + c0 * 8] = b0;
        *(uint4*)&sB[r1 * 40 + c0 * 8] = b1;
        __syncthreads();

        bf16x8 af[4], bg[4];
#pragma unroll
        for (int t = 0; t < 4; ++t) {
            af[t] = *(const bf16x8*)&sA[(wm * 64 + t * 16 + l16) * 40 + quad * 8];
            bg[t] = *(const bf16x8*)&sB[(wn * 64 + t * 16 + l16) * 40 + quad * 8];
        }
#pragma unroll
        for (int mt = 0; mt < 4; ++mt)
#pragma unroll
            for (int nt = 0; nt < 4; ++nt)
                acc[mt][nt] = __builtin_amdgcn_mfma_f32_16x16x32_bf16(
                    af[mt], bg[nt], acc[mt][nt], 0, 0, 0);
    }

    float* Cf = (float*)C + (size_t)blockIdx.z * M * N;
#pragma unroll
    for (int mt = 0; mt < 4; ++mt) {
#pragma unroll
        for (int r = 0; r < 4; ++r) {
            const int row = bm * 128 + wm * 64 + mt * 16 + quad * 4 + r;
#pragma unroll
            for (int nt = 0; nt < 4; ++nt) {
                const int col = bn * 128 + wn * 64 + nt * 16 + l16;
                if (STORE_F32)
                    Cf[(size_t)row * N + col] = acc[mt][nt][r];
                else
                    ((u16*)C)[(size_t)row * N + col] = f2bf(acc[mt][nt][r]);
            }
        }
    }
}

// sum P parts of length n (floats), float4-vectorized
__global__ __launch_bounds__(256) void reduce_parts(const float* __restrict__ src,
                                                    float* __restrict__ dst,
                                                    int n4, int parts) {
    const int i = blockIdx.x * 256 + threadIdx.x;
    if (i >= n4) return;
    float4 s = ((const float4*)src)[i];
    for (int p = 1; p < parts; ++p) {
        const float4 v = ((const float4*)src)[(size_t)p * n4 + i];
        s.x += v.x; s.y += v.y; s.z += v.z; s.w += v.w;
    }
    ((float4*)dst)[i] = s;
}

// ---------------------------------------------------------------------------
// Depthwise causal conv (D_CONV=4) + SiLU.  xz bf16 (B*L, 4096) -> xb16 bf16.
// ---------------------------------------------------------------------------
__global__ __launch_bounds__(256) void conv_silu(const u16* __restrict__ xz,
                                                 const float* __restrict__ par,
                                                 u16* __restrict__ xb16) {
    const int idx = blockIdx.x * 256 + threadIdx.x;  // over 2*1024*2048
    const int d = idx & 2047;
    const int bl = idx >> 11;
    const int l = bl & 1023;
    float acc = par[P_CONVB + d];
#pragma unroll
    for (int k = 0; k < 4; ++k) {
        const int ls = l + k - 3;
        if (ls >= 0)
            acc = fmaf(bf2f(xz[(size_t)(bl + (ls - l)) * 4096 + d]),
                       par[P_CONVW + d * 4 + k], acc);
    }
    const float s = acc / (1.f + __expf(-acc));
    xb16[idx] = f2bf(s);
}

// ---------------------------------------------------------------------------
// Chunked parallel scan, pass 1: per (b, d, chunk) compute per-n
// P = prod(dA) and S = chunk-local h (starting from 0).  16 n in registers.
// ---------------------------------------------------------------------------
__global__ __launch_bounds__(256) void scan_p1(const u16* __restrict__ xb16,
                                               const float* __restrict__ proj,
                                               const float* __restrict__ par,
                                               float* __restrict__ PS) {
    const int d = blockIdx.x * 256 + threadIdx.x;   // grid.x = 8
    const int c = blockIdx.y;                       // 0..CCH-1
    const int b = blockIdx.z;                       // 0..1
    __shared__ float sp[CT][33];
    const size_t row0 = (size_t)b * 1024 + c * CT;
    for (int f = threadIdx.x; f < CT * 33; f += 256) {
        const int i = f / 33, j = f - i * 33;
        sp[i][j] = proj[(row0 + i) * PSTRIDE + j];
    }
    float Aneg[16];
#pragma unroll
    for (int n = 0; n < 16; ++n) Aneg[n] = -__expf(par[P_ALOG + d * 16 + n]);
    const float dtw = par[P_DTW + d], dtb = par[P_DTB + d];
    __syncthreads();

    float h[16] = {}, P[16];
#pragma unroll
    for (int n = 0; n < 16; ++n) P[n] = 1.f;

    float xv = bf2f(xb16[row0 * 2048 + d]);
    for (int i = 0; i < CT; ++i) {
        const float xv_next = (i + 1 < CT) ? bf2f(xb16[(row0 + i + 1) * 2048 + d]) : 0.f;
        const float dtin = sp[i][0];
        const float darg = fmaf(dtin, dtw, dtb);
        const float dt = (darg > 20.f) ? darg : __logf(1.f + __expf(darg));
        const float xdt = xv * dt;
#pragma unroll
        for (int n = 0; n < 16; ++n) {
            const float dA = __expf(dt * Aneg[n]);
            P[n] *= dA;
            h[n] = fmaf(dA, h[n], xdt * sp[i][1 + n]);
        }
        xv = xv_next;
    }
    const size_t base = (((size_t)b * CCH + c) * 16) * 2048 + d;
#pragma unroll
    for (int n = 0; n < 16; ++n) {
        PS[base + (size_t)n * 2048] = P[n];
        PS[CHUNKTOT + base + (size_t)n * 2048] = h[n];
    }
}

// ---------------------------------------------------------------------------
// Combine: per (b,d,n), serial scan over CCH chunks: H_c = state before chunk c.
// ---------------------------------------------------------------------------
__global__ __launch_bounds__(256) void scan_comb(const float* __restrict__ PS,
                                                 float* __restrict__ H) {
    const int t = blockIdx.x * 256 + threadIdx.x;  // 65536 total
    const int d = t & 2047;
    const int n = (t >> 11) & 15;
    const int b = t >> 15;
    float h = 0.f;
#pragma unroll
    for (int c = 0; c < CCH; ++c) {
        const size_t idx = (((size_t)b * CCH + c) * 16 + n) * 2048 + d;
        H[idx] = h;
        h = fmaf(PS[idx], h, PS[CHUNKTOT + idx]);
    }
}

// ---------------------------------------------------------------------------
// Pass 2: replay each chunk from its true initial state H_c, emit y (bf16).
// ---------------------------------------------------------------------------
__global__ __launch_bounds__(256) void scan_p2(const u16* __restrict__ xb16,
                                               const float* __restrict__ proj,
                                               const float* __restrict__ par,
                                               const float* __restrict__ H,
                                               u16* __restrict__ y) {
    const int d = blockIdx.x * 256 + threadIdx.x;
    const int c = blockIdx.y;
    const int b = blockIdx.z;
    __shared__ float sp[CT][33];
    const size_t row0 = (size_t)b * 1024 + c * CT;
    for (int f = threadIdx.x; f < CT * 33; f += 256) {
        const int i = f / 33, j = f - i * 33;
        sp[i][j] = proj[(row0 + i) * PSTRIDE + j];
    }
    float Aneg[16], h[16];
    const size_t hbase = (((size_t)b * CCH + c) * 16) * 2048 + d;
#pragma unroll
    for (int n = 0; n < 16; ++n) {
        Aneg[n] = -__expf(par[P_ALOG + d * 16 + n]);
        h[n] = H[hbase + (size_t)n * 2048];
    }
    const float dtw = par[P_DTW + d], dtb = par[P_DTB + d];
    const float Dp = par[P_DPAR + d];
    __syncthreads();

    float xv = bf2f(xb16[row0 * 2048 + d]);
    for (int i = 0; i < CT; ++i) {
        const float xv_next = (i + 1 < CT) ? bf2f(xb16[(row0 + i + 1) * 2048 + d]) : 0.f;
        const float dtin = sp[i][0];
        const float darg = fmaf(dtin, dtw, dtb);
        const float dt = (darg > 20.f) ? darg : __logf(1.f + __expf(darg));
        const float xdt = xv * dt;
        float acc = 0.f;
#pragma unroll
        for (int n = 0; n < 16; ++n) {
            const float dA = __expf(dt * Aneg[n]);
            h[n] = fmaf(dA, h[n], xdt * sp[i][1 + n]);
            acc = fmaf(h[n], sp[i][17 + n], acc);
        }
        y[(row0 + i) * 2048 + d] = f2bf(fmaf(xv, Dp, acc));
        xv = xv_next;
    }
}

// ---------------------------------------------------------------------------
// LayerNorm over D_INNER + *silu(z); y bf16 in, yn bf16 out.
// ---------------------------------------------------------------------------
__global__ __launch_bounds__(256) void ln_silu(const u16* __restrict__ y,
                                               const u16* __restrict__ xz,
                                               const float* __restrict__ par,
                                               u16* __restrict__ yn) {
    const int row = blockIdx.x;
    const int tid = threadIdx.x;
    const int lane = tid & 63, wave = tid >> 6;
    float v[8];
    float s = 0.f, s2 = 0.f;
#pragma unroll
    for (int i = 0; i < 8; ++i) {
        v[i] = bf2f(y[(size_t)row * 2048 + tid + i * 256]);
        s += v[i];
        s2 = fmaf(v[i], v[i], s2);
    }
    s += __shfl_xor(s, 1); s2 += __shfl_xor(s2, 1);
    s += __shfl_xor(s, 2); s2 += __shfl_xor(s2, 2);
    s += __shfl_xor(s, 4); s2 += __shfl_xor(s2, 4);
    s += __shfl_xor(s, 8); s2 += __shfl_xor(s2, 8);
    s += __shfl_xor(s, 16); s2 += __shfl_xor(s2, 16);
    s += __shfl_xor(s, 32); s2 += __shfl_xor(s2, 32);
    __shared__ float rs[4], rs2[4];
    if (lane == 0) { rs[wave] = s; rs2[wave] = s2; }
    __syncthreads();
    const float ts = rs[0] + rs[1] + rs[2] + rs[3];
    const float ts2 = rs2[0] + rs2[1] + rs2[2] + rs2[3];
    const float mu = ts * (1.f / 2048.f);
    const float var = ts2 * (1.f / 2048.f) - mu * mu;
    const float rstd = rsqrtf(var + 1e-5f);
#pragma unroll
    for (int i = 0; i < 8; ++i) {
        const int d = tid + i * 256;
        float t = (v[i] - mu) * rstd * par[P_LNG + d] + par[P_LNB + d];
        const float z = bf2f(xz[(size_t)row * 4096 + 2048 + d]);
        t *= z / (1.f + __expf(-z));
        yn[(size_t)row * 2048 + d] = f2bf(t);
    }
}

// ---------------------------------------------------------------------------
extern "C" void kernel_launch(void* const* d_in, const int* in_sizes, int n_in,
                              void* d_out, int out_size, void* d_ws, size_t ws_size,
                              hipStream_t stream) {
    const void* x         = d_in[0];   // (2,1024,1024) fp32
    const void* in_proj_w = d_in[1];
    const void* conv_w    = d_in[2];
    const void* conv_b    = d_in[3];
    const void* x_proj_w  = d_in[4];
    const void* A_log     = d_in[5];
    const void* D_param   = d_in[6];
    const void* dt_w      = d_in[7];
    const void* dt_b      = d_in[8];
    const void* out_w     = d_in[9];
    const void* ln_g      = d_in[10];
    const void* ln_b      = d_in[11];
    const u16* dp = (const u16*)D_param;

    // workspace layout — 73.7 MB total
    float* cpar = (float*)d_ws;              // 53,248 f32
    u16* cx     = (u16*)(cpar + P_TOTAL);    // 2,097,152 u16 (4 MB)
    u16* cw1    = cx + 2097152;              // 4,194,304 u16 (8 MB)
    u16* cwo    = cw1 + 4194304;             // 2,097,152 u16 (4 MB)
    u16* xz     = cwo + 2097152;             // 8,388,608 u16 (16 MB)
    u16* xb16   = xz + 8388608;              // 4,194,304 u16 (8 MB)
    u16* y      = xb16 + 4194304;            // 4,194,304 u16 (8 MB)
    u16* wpad   = y + 4194304;               // 262,144 u16   (0.5 MB)
    float* proj = (float*)(wpad + 262144);   // 2048*128 f32  (1 MB)
    float* PS   = proj + 262144;             // 2*CHUNKTOT f32 (16 MB)
    float* H    = PS + 2 * CHUNKTOT;         // CHUNKTOT f32   (8 MB)
    // overlays:
    float* xpart = (float*)cx;               // 8*2048*128 f32 (8 MB) — after gemm1
    float* gpart = PS;                       // 2*2048*1024 f32 (16 MB) — after scan
    u16* yn      = xb16;                     // xb16 dead after scan_p2

    // 0. canonicalize params + convert GEMM operands to bf16
    ParamPtrs pp;
    pp.p[0] = conv_w; pp.p[1] = conv_b; pp.p[2] = A_log; pp.p[3] = D_param;
    pp.p[4] = dt_w;   pp.p[5] = dt_b;   pp.p[6] = ln_g;  pp.p[7] = ln_b;
    canon_params<<<P_TOTAL / 256, 256, 0, stream>>>(pp, cpar, dp);
    canon_multi<<<CV_TOT / 256, 256, 0, stream>>>(x, in_proj_w, out_w, cx, dp);
    canon_wpad<<<256, 256, 0, stream>>>(x_proj_w, wpad, dp);

    // 1. in_proj: xz = x @ in_proj_w^T   (M=2048, N=4096, K=1024), bf16 out
    gemm_bt<false><<<dim3(16, 32, 1), 256, 0, stream>>>(cx, cw1, xz, 2048, 4096, 1024, 1024, 1024);
    // 2. causal conv4 + silu -> bf16
    conv_silu<<<16384, 256, 0, stream>>>(xz, cpar, xb16);
    // 3. x_proj GEMM, split-K 8x: xpart[z] = xb16 @ wpad^T (K seg 256)
    gemm_bt<true><<<dim3(16, 1, 8), 256, 0, stream>>>(xb16, wpad, xpart, 2048, 128, 256, 2048, 2048);
    reduce_parts<<<256, 256, 0, stream>>>(xpart, proj, 65536, 8);
    // 4. chunked parallel scan (CCH=32 chunks of CT=32)
    scan_p1<<<dim3(8, CCH, 2), 256, 0, stream>>>(xb16, proj, cpar, PS);
    scan_comb<<<256, 256, 0, stream>>>(PS, H);
    scan_p2<<<dim3(8, CCH, 2), 256, 0, stream>>>(xb16, proj, cpar, H, y);
    // 5. layernorm + silu(z) gate (yn overlays xb16)
    ln_silu<<<2048, 256, 0, stream>>>(y, xz, cpar, yn);
    // 6. out proj, split-K 2x: gpart[z] = yn @ out_w^T (K seg 1024), then reduce
    gemm_bt<true><<<dim3(16, 8, 2), 256, 0, stream>>>(yn, cwo, gpart, 2048, 1024, 1024, 2048, 2048);
    reduce_parts<<<2048, 256, 0, stream>>>(gpart, (float*)d_out, 524288, 2);
}

// Round 9
// 256.066 us; speedup vs baseline: 2.8091x; 1.0181x over previous
//
#include <hip/hip_runtime.h>

typedef unsigned short u16;
typedef unsigned int u32;
typedef __bf16 bf16x8 __attribute__((ext_vector_type(8)));
typedef float f32x4 __attribute__((ext_vector_type(4)));

__device__ __forceinline__ float bf2f(u16 b) {
    return __uint_as_float(((u32)b) << 16);
}
__device__ __forceinline__ u16 f2bf(float f) {
    u32 u = __float_as_uint(f);
    return (u16)((u + 0x7fffu + ((u >> 16) & 1u)) >> 16);
}

// fp32 canonical param block (element offsets)
#define P_CONVW 0       // 2048*4
#define P_CONVB 8192    // 2048
#define P_ALOG  10240   // 2048*16
#define P_DPAR  43008   // 2048
#define P_DTW   45056   // 2048
#define P_DTB   47104   // 2048
#define P_LNG   49152   // 2048
#define P_LNB   51200   // 2048
#define P_TOTAL 53248

// scan chunking
#define CCH 32            // chunks over L=1024
#define CT  32            // timesteps per chunk
#define CHUNKTOT 2097152  // B*CCH*16*2048
#define PSTRIDE 128       // proj row stride (N padded for MFMA)

struct ParamPtrs { const void* p[8]; };

__global__ __launch_bounds__(256) void canon_params(ParamPtrs pp, float* __restrict__ dst,
                                                    const u16* __restrict__ dp) {
    const bool isbf = (dp[0] != 0);
    const int i = blockIdx.x * 256 + threadIdx.x;  // exact grid over P_TOTAL
    int seg, off;
    if (i < P_CONVB)      { seg = 0; off = i; }
    else if (i < P_ALOG)  { seg = 1; off = i - P_CONVB; }
    else if (i < P_DPAR)  { seg = 2; off = i - P_ALOG; }
    else if (i < P_DTW)   { seg = 3; off = i - P_DPAR; }
    else if (i < P_DTB)   { seg = 4; off = i - P_DTW; }
    else if (i < P_LNG)   { seg = 5; off = i - P_DTB; }
    else if (i < P_LNB)   { seg = 6; off = i - P_LNG; }
    else                  { seg = 7; off = i - P_LNB; }
    dst[i] = isbf ? bf2f(((const u16*)pp.p[seg])[off]) : ((const float*)pp.p[seg])[off];
}

// convert x / in_proj_w / out_w to bf16 into the contiguous cx|cw1|cwo region.
#define CV_X   524288
#define CV_W1  1572864
#define CV_TOT 2097152
__global__ __launch_bounds__(256) void canon_multi(const void* __restrict__ sx,
                                                   const void* __restrict__ sw1,
                                                   const void* __restrict__ swo,
                                                   u16* __restrict__ dst,
                                                   const u16* __restrict__ dp) {
    const bool isbf = (dp[0] != 0);
    const int i = blockIdx.x * 256 + threadIdx.x;
    if (i >= CV_TOT) return;
    const void* src;
    int off;
    if (i < CV_X)       { src = sx;  off = i; }
    else if (i < CV_W1) { src = sw1; off = i - CV_X; }
    else                { src = swo; off = i - CV_W1; }
    if (isbf) {
        ((uint2*)dst)[i] = ((const uint2*)src)[off];
    } else {
        const float4 v = ((const float4*)src)[off];
        uint2 o;
        o.x = (u32)f2bf(v.x) | ((u32)f2bf(v.y) << 16);
        o.y = (u32)f2bf(v.z) | ((u32)f2bf(v.w) << 16);
        ((uint2*)dst)[i] = o;
    }
}

// x_proj_w (33,2048) -> zero-padded bf16 (128,2048)
__global__ __launch_bounds__(256) void canon_wpad(const void* __restrict__ src,
                                                  u16* __restrict__ dst,
                                                  const u16* __restrict__ dp) {
    const bool isbf = (dp[0] != 0);
    const int i = blockIdx.x * 256 + threadIdx.x;  // over 128*2048/4 = 65536
    const int idx = i * 4;
    const int row = idx >> 11;
    u16 o[4];
#pragma unroll
    for (int q = 0; q < 4; ++q) {
        float v = 0.f;
        if (row < 33)
            v = isbf ? bf2f(((const u16*)src)[idx + q]) : ((const float*)src)[idx + q];
        o[q] = f2bf(v);
    }
    *(uint2*)&dst[idx] = *(uint2*)o;
}

// ---------------------------------------------------------------------------
// GEMM: C[M,N] = A[M, kbase:kbase+Kseg] * W[N, same]^T, bf16 in.
// Staging via __builtin_amdgcn_global_load_lds width=16 (m97 structure):
// LDS rows unpadded (stride 32 u16 = 64B); wave w issue q covers rows
// (w+4q)*16..+15, lane l -> row l>>2, 16B chunk l&3, dst = base + l*16.
// blockIdx.z selects a K segment; fp32 partial written to C + z*M*N.
// ---------------------------------------------------------------------------
template <bool STORE_F32>
__global__ __launch_bounds__(256) void gemm_bt(const u16* __restrict__ A,
                                               const u16* __restrict__ Bw,
                                               void* __restrict__ C,
                                               int M, int N, int Kseg,
                                               int lda, int ldb) {
    const int bm = blockIdx.x;
    const int bn = blockIdx.y;
    const int kbase = blockIdx.z * Kseg;
    const int tid = threadIdx.x;
    const int lane = tid & 63;
    const int wave = tid >> 6;
    const int wm = wave >> 1, wn = wave & 1;
    const int l16 = lane & 15, quad = lane >> 4;

    __shared__ __align__(16) u16 sA[128 * 32];
    __shared__ __align__(16) u16 sB[128 * 32];

    f32x4 acc[4][4] = {};

    // staging map (per wave-issue): row group g = wave + 4*q
    const int rsub = lane >> 2;          // 0..15 row within group
    const int csub = (lane & 3) * 8;     // u16 col within 32-col tile

    for (int k0 = 0; k0 < Kseg; k0 += 32) {
        const int kc = kbase + k0 + csub;
        __syncthreads();  // previous iteration's readers done
#pragma unroll
        for (int q = 0; q < 2; ++q) {
            const int g = wave + 4 * q;
            const int row = g * 16 + rsub;
            __builtin_amdgcn_global_load_lds(
                (const u32*)&A[(size_t)(bm * 128 + row) * lda + kc],
                (u32*)&sA[g * 512], 16, 0, 0);
            __builtin_amdgcn_global_load_lds(
                (const u32*)&Bw[(size_t)(bn * 128 + row) * ldb + kc],
                (u32*)&sB[g * 512], 16, 0, 0);
        }
        __syncthreads();  // drain global_load_lds (compiler emits vmcnt(0))

        bf16x8 af[4], bg[4];
#pragma unroll
        for (int t = 0; t < 4; ++t) {
            af[t] = *(const bf16x8*)&sA[(wm * 64 + t * 16 + l16) * 32 + quad * 8];
            bg[t] = *(const bf16x8*)&sB[(wn * 64 + t * 16 + l16) * 32 + quad * 8];
        }
#pragma unroll
        for (int mt = 0; mt < 4; ++mt)
#pragma unroll
            for (int nt = 0; nt < 4; ++nt)
                acc[mt][nt] = __builtin_amdgcn_mfma_f32_16x16x32_bf16(
                    af[mt], bg[nt], acc[mt][nt], 0, 0, 0);
    }

    float* Cf = (float*)C + (size_t)blockIdx.z * M * N;
#pragma unroll
    for (int mt = 0; mt < 4; ++mt) {
#pragma unroll
        for (int r = 0; r < 4; ++r) {
            const int row = bm * 128 + wm * 64 + mt * 16 + quad * 4 + r;
#pragma unroll
            for (int nt = 0; nt < 4; ++nt) {
                const int col = bn * 128 + wn * 64 + nt * 16 + l16;
                if (STORE_F32)
                    Cf[(size_t)row * N + col] = acc[mt][nt][r];
                else
                    ((u16*)C)[(size_t)row * N + col] = f2bf(acc[mt][nt][r]);
            }
        }
    }
}

// sum P parts of length n (floats), float4-vectorized
__global__ __launch_bounds__(256) void reduce_parts(const float* __restrict__ src,
                                                    float* __restrict__ dst,
                                                    int n4, int parts) {
    const int i = blockIdx.x * 256 + threadIdx.x;
    if (i >= n4) return;
    float4 s = ((const float4*)src)[i];
    for (int p = 1; p < parts; ++p) {
        const float4 v = ((const float4*)src)[(size_t)p * n4 + i];
        s.x += v.x; s.y += v.y; s.z += v.z; s.w += v.w;
    }
    ((float4*)dst)[i] = s;
}

// ---------------------------------------------------------------------------
// Depthwise causal conv (D_CONV=4) + SiLU.  xz bf16 (B*L, 4096) -> xb16 bf16.
// ---------------------------------------------------------------------------
__global__ __launch_bounds__(256) void conv_silu(const u16* __restrict__ xz,
                                                 const float* __restrict__ par,
                                                 u16* __restrict__ xb16) {
    const int idx = blockIdx.x * 256 + threadIdx.x;  // over 2*1024*2048
    const int d = idx & 2047;
    const int bl = idx >> 11;
    const int l = bl & 1023;
    float acc = par[P_CONVB + d];
#pragma unroll
    for (int k = 0; k < 4; ++k) {
        const int ls = l + k - 3;
        if (ls >= 0)
            acc = fmaf(bf2f(xz[(size_t)(bl + (ls - l)) * 4096 + d]),
                       par[P_CONVW + d * 4 + k], acc);
    }
    const float s = acc / (1.f + __expf(-acc));
    xb16[idx] = f2bf(s);
}

// ---------------------------------------------------------------------------
// Chunked parallel scan, pass 1: per (b, d, chunk) compute per-n
// P = prod(dA) and S = chunk-local h (starting from 0).  16 n in registers.
// ---------------------------------------------------------------------------
__global__ __launch_bounds__(256) void scan_p1(const u16* __restrict__ xb16,
                                               const float* __restrict__ proj,
                                               const float* __restrict__ par,
                                               float* __restrict__ PS) {
    const int d = blockIdx.x * 256 + threadIdx.x;   // grid.x = 8
    const int c = blockIdx.y;                       // 0..CCH-1
    const int b = blockIdx.z;                       // 0..1
    __shared__ float sp[CT][33];
    const size_t row0 = (size_t)b * 1024 + c * CT;
    for (int f = threadIdx.x; f < CT * 33; f += 256) {
        const int i = f / 33, j = f - i * 33;
        sp[i][j] = proj[(row0 + i) * PSTRIDE + j];
    }
    float Aneg[16];
#pragma unroll
    for (int n = 0; n < 16; ++n) Aneg[n] = -__expf(par[P_ALOG + d * 16 + n]);
    const float dtw = par[P_DTW + d], dtb = par[P_DTB + d];
    __syncthreads();

    float h[16] = {}, P[16];
#pragma unroll
    for (int n = 0; n < 16; ++n) P[n] = 1.f;

    float xv = bf2f(xb16[row0 * 2048 + d]);
    for (int i = 0; i < CT; ++i) {
        const float xv_next = (i + 1 < CT) ? bf2f(xb16[(row0 + i + 1) * 2048 + d]) : 0.f;
        const float dtin = sp[i][0];
        const float darg = fmaf(dtin, dtw, dtb);
        const float dt = (darg > 20.f) ? darg : __logf(1.f + __expf(darg));
        const float xdt = xv * dt;
#pragma unroll
        for (int n = 0; n < 16; ++n) {
            const float dA = __expf(dt * Aneg[n]);
            P[n] *= dA;
            h[n] = fmaf(dA, h[n], xdt * sp[i][1 + n]);
        }
        xv = xv_next;
    }
    const size_t base = (((size_t)b * CCH + c) * 16) * 2048 + d;
#pragma unroll
    for (int n = 0; n < 16; ++n) {
        PS[base + (size_t)n * 2048] = P[n];
        PS[CHUNKTOT + base + (size_t)n * 2048] = h[n];
    }
}

// ---------------------------------------------------------------------------
// Combine: per (b,d,n), serial scan over CCH chunks: H_c = state before chunk c.
// ---------------------------------------------------------------------------
__global__ __launch_bounds__(256) void scan_comb(const float* __restrict__ PS,
                                                 float* __restrict__ H) {
    const int t = blockIdx.x * 256 + threadIdx.x;  // 65536 total
    const int d = t & 2047;
    const int n = (t >> 11) & 15;
    const int b = t >> 15;
    float h = 0.f;
#pragma unroll
    for (int c = 0; c < CCH; ++c) {
        const size_t idx = (((size_t)b * CCH + c) * 16 + n) * 2048 + d;
        H[idx] = h;
        h = fmaf(PS[idx], h, PS[CHUNKTOT + idx]);
    }
}

// ---------------------------------------------------------------------------
// Pass 2: replay each chunk from its true initial state H_c, emit y (bf16).
// ---------------------------------------------------------------------------
__global__ __launch_bounds__(256) void scan_p2(const u16* __restrict__ xb16,
                                               const float* __restrict__ proj,
                                               const float* __restrict__ par,
                                               const float* __restrict__ H,
                                               u16* __restrict__ y) {
    const int d = blockIdx.x * 256 + threadIdx.x;
    const int c = blockIdx.y;
    const int b = blockIdx.z;
    __shared__ float sp[CT][33];
    const size_t row0 = (size_t)b * 1024 + c * CT;
    for (int f = threadIdx.x; f < CT * 33; f += 256) {
        const int i = f / 33, j = f - i * 33;
        sp[i][j] = proj[(row0 + i) * PSTRIDE + j];
    }
    float Aneg[16], h[16];
    const size_t hbase = (((size_t)b * CCH + c) * 16) * 2048 + d;
#pragma unroll
    for (int n = 0; n < 16; ++n) {
        Aneg[n] = -__expf(par[P_ALOG + d * 16 + n]);
        h[n] = H[hbase + (size_t)n * 2048];
    }
    const float dtw = par[P_DTW + d], dtb = par[P_DTB + d];
    const float Dp = par[P_DPAR + d];
    __syncthreads();

    float xv = bf2f(xb16[row0 * 2048 + d]);
    for (int i = 0; i < CT; ++i) {
        const float xv_next = (i + 1 < CT) ? bf2f(xb16[(row0 + i + 1) * 2048 + d]) : 0.f;
        const float dtin = sp[i][0];
        const float darg = fmaf(dtin, dtw, dtb);
        const float dt = (darg > 20.f) ? darg : __logf(1.f + __expf(darg));
        const float xdt = xv * dt;
        float acc = 0.f;
#pragma unroll
        for (int n = 0; n < 16; ++n) {
            const float dA = __expf(dt * Aneg[n]);
            h[n] = fmaf(dA, h[n], xdt * sp[i][1 + n]);
            acc = fmaf(h[n], sp[i][17 + n], acc);
        }
        y[(row0 + i) * 2048 + d] = f2bf(fmaf(xv, Dp, acc));
        xv = xv_next;
    }
}

// ---------------------------------------------------------------------------
// LayerNorm over D_INNER + *silu(z); y bf16 in, yn bf16 out.
// ---------------------------------------------------------------------------
__global__ __launch_bounds__(256) void ln_silu(const u16* __restrict__ y,
                                               const u16* __restrict__ xz,
                                               const float* __restrict__ par,
                                               u16* __restrict__ yn) {
    const int row = blockIdx.x;
    const int tid = threadIdx.x;
    const int lane = tid & 63, wave = tid >> 6;
    float v[8];
    float s = 0.f, s2 = 0.f;
#pragma unroll
    for (int i = 0; i < 8; ++i) {
        v[i] = bf2f(y[(size_t)row * 2048 + tid + i * 256]);
        s += v[i];
        s2 = fmaf(v[i], v[i], s2);
    }
    s += __shfl_xor(s, 1); s2 += __shfl_xor(s2, 1);
    s += __shfl_xor(s, 2); s2 += __shfl_xor(s2, 2);
    s += __shfl_xor(s, 4); s2 += __shfl_xor(s2, 4);
    s += __shfl_xor(s, 8); s2 += __shfl_xor(s2, 8);
    s += __shfl_xor(s, 16); s2 += __shfl_xor(s2, 16);
    s += __shfl_xor(s, 32); s2 += __shfl_xor(s2, 32);
    __shared__ float rs[4], rs2[4];
    if (lane == 0) { rs[wave] = s; rs2[wave] = s2; }
    __syncthreads();
    const float ts = rs[0] + rs[1] + rs[2] + rs[3];
    const float ts2 = rs2[0] + rs2[1] + rs2[2] + rs2[3];
    const float mu = ts * (1.f / 2048.f);
    const float var = ts2 * (1.f / 2048.f) - mu * mu;
    const float rstd = rsqrtf(var + 1e-5f);
#pragma unroll
    for (int i = 0; i < 8; ++i) {
        const int d = tid + i * 256;
        float t = (v[i] - mu) * rstd * par[P_LNG + d] + par[P_LNB + d];
        const float z = bf2f(xz[(size_t)row * 4096 + 2048 + d]);
        t *= z / (1.f + __expf(-z));
        yn[(size_t)row * 2048 + d] = f2bf(t);
    }
}

// ---------------------------------------------------------------------------
extern "C" void kernel_launch(void* const* d_in, const int* in_sizes, int n_in,
                              void* d_out, int out_size, void* d_ws, size_t ws_size,
                              hipStream_t stream) {
    const void* x         = d_in[0];   // (2,1024,1024) fp32
    const void* in_proj_w = d_in[1];
    const void* conv_w    = d_in[2];
    const void* conv_b    = d_in[3];
    const void* x_proj_w  = d_in[4];
    const void* A_log     = d_in[5];
    const void* D_param   = d_in[6];
    const void* dt_w      = d_in[7];
    const void* dt_b      = d_in[8];
    const void* out_w     = d_in[9];
    const void* ln_g      = d_in[10];
    const void* ln_b      = d_in[11];
    const u16* dp = (const u16*)D_param;

    // workspace layout — 73.7 MB total
    float* cpar = (float*)d_ws;              // 53,248 f32
    u16* cx     = (u16*)(cpar + P_TOTAL);    // 2,097,152 u16 (4 MB)
    u16* cw1    = cx + 2097152;              // 4,194,304 u16 (8 MB)
    u16* cwo    = cw1 + 4194304;             // 2,097,152 u16 (4 MB)
    u16* xz     = cwo + 2097152;             // 8,388,608 u16 (16 MB)
    u16* xb16   = xz + 8388608;              // 4,194,304 u16 (8 MB)
    u16* y      = xb16 + 4194304;            // 4,194,304 u16 (8 MB)
    u16* wpad   = y + 4194304;               // 262,144 u16   (0.5 MB)
    float* proj = (float*)(wpad + 262144);   // 2048*128 f32  (1 MB)
    float* PS   = proj + 262144;             // 2*CHUNKTOT f32 (16 MB)
    float* H    = PS + 2 * CHUNKTOT;         // CHUNKTOT f32   (8 MB)
    // overlays:
    float* xpart = (float*)cx;               // 8*2048*128 f32 (8 MB) — after gemm1
    float* gpart = PS;                       // 2*2048*1024 f32 (16 MB) — after scan
    u16* yn      = xb16;                     // xb16 dead after scan_p2

    // 0. canonicalize params + convert GEMM operands to bf16
    ParamPtrs pp;
    pp.p[0] = conv_w; pp.p[1] = conv_b; pp.p[2] = A_log; pp.p[3] = D_param;
    pp.p[4] = dt_w;   pp.p[5] = dt_b;   pp.p[6] = ln_g;  pp.p[7] = ln_b;
    canon_params<<<P_TOTAL / 256, 256, 0, stream>>>(pp, cpar, dp);
    canon_multi<<<CV_TOT / 256, 256, 0, stream>>>(x, in_proj_w, out_w, cx, dp);
    canon_wpad<<<256, 256, 0, stream>>>(x_proj_w, wpad, dp);

    // 1. in_proj: xz = x @ in_proj_w^T   (M=2048, N=4096, K=1024), bf16 out
    gemm_bt<false><<<dim3(16, 32, 1), 256, 0, stream>>>(cx, cw1, xz, 2048, 4096, 1024, 1024, 1024);
    // 2. causal conv4 + silu -> bf16
    conv_silu<<<16384, 256, 0, stream>>>(xz, cpar, xb16);
    // 3. x_proj GEMM, split-K 8x: xpart[z] = xb16 @ wpad^T (K seg 256)
    gemm_bt<true><<<dim3(16, 1, 8), 256, 0, stream>>>(xb16, wpad, xpart, 2048, 128, 256, 2048, 2048);
    reduce_parts<<<256, 256, 0, stream>>>(xpart, proj, 65536, 8);
    // 4. chunked parallel scan (CCH=32 chunks of CT=32)
    scan_p1<<<dim3(8, CCH, 2), 256, 0, stream>>>(xb16, proj, cpar, PS);
    scan_comb<<<256, 256, 0, stream>>>(PS, H);
    scan_p2<<<dim3(8, CCH, 2), 256, 0, stream>>>(xb16, proj, cpar, H, y);
    // 5. layernorm + silu(z) gate (yn overlays xb16)
    ln_silu<<<2048, 256, 0, stream>>>(y, xz, cpar, yn);
    // 6. out proj, split-K 2x: gpart[z] = yn @ out_w^T (K seg 1024), then reduce
    gemm_bt<true><<<dim3(16, 8, 2), 256, 0, stream>>>(yn, cwo, gpart, 2048, 1024, 1024, 2048, 2048);
    reduce_parts<<<2048, 256, 0, stream>>>(gpart, (float*)d_out, 524288, 2);
}